// Round 18
// baseline (202.731 us; speedup 1.0000x reference)
//
#include <hip/hip_runtime.h>
#include <hip/hip_bf16.h>

#define B 2
#define S 8192
#define H 16
#define D 64
#define NB 32          // S / BS
#define BS 256
#define SAMP 256
#define BH (B*H)
#define BHS (B*H*S)
#define BSHD (B*S*H*D)
#define LOG32 3.4657359027997265f   // log(8192/256)

typedef float f32x4 __attribute__((ext_vector_type(4)));
typedef short bf16x8 __attribute__((ext_vector_type(8)));

// Packed f32->bf16 (RNE), single HW instruction.
__device__ __forceinline__ unsigned int pack2(float a, float b) {
    unsigned int r;
    asm("v_cvt_pk_bf16_f32 %0, %1, %2" : "=v"(r) : "v"(a), "v"(b));
    return r;
}

// ---------------------------------------------------------------------------
// Kernel 1: LSH hash (Q and K) + bf16 pack of K.  (unchanged — at its
// cold-read floor, ~40 us)
// ---------------------------------------------------------------------------
#define HP 34   // tile pitch in dwords (136 B / row)

__global__ __launch_bounds__(256, 3) void k_hash(const float* __restrict__ q,
                                                 const float* __restrict__ k,
                                                 const float* __restrict__ pd,
                                                 int* __restrict__ hq,
                                                 int* __restrict__ hk,
                                                 unsigned short* __restrict__ kbf) {
    __shared__ float spd4[4 * 520];          // 8320 B
    __shared__ unsigned int tile[256 * HP];  // 34816 B
    __shared__ int ht[16][16];               // 1024 B
    const int t = threadIdx.x;
    for (int i = t; i < 512; i += 256) {
        const float val = pd[i];
        spd4[i] = val; spd4[520 + i] = val;
        spd4[1040 + i] = val; spd4[1560 + i] = val;
    }
    __syncthreads();

    const bool isK = blockIdx.x >= 1024;
    const int  blk = blockIdx.x & 1023;
    const float* src = isK ? k : q;
    int* hdst = isK ? hk : hq;

    const int lane = t & 63;
    const int c    = lane & 3;                          // dim-quarter owner
    const int rql  = (t >> 6) * 64 + (lane >> 2) * 4;   // local row base of quad
    const int rowq = blk * 256 + rql;
    const float* sp = spd4 + c * 520;

    float d[4][8];
#pragma unroll
    for (int rr = 0; rr < 4; ++rr)
#pragma unroll
        for (int p = 0; p < 8; ++p) d[rr][p] = 0.f;

#pragma unroll
    for (int j = 0; j < 4; ++j) {
        float4 x[4];
#pragma unroll
        for (int rr = 0; rr < 4; ++rr)
            x[rr] = *(const float4*)(src + ((rowq + rr) << 6) + j * 16 + c * 4);

        if (isK) {
#pragma unroll
            for (int rr = 0; rr < 4; ++rr) {
                uint2 u2;
                u2.x = pack2(x[rr].x, x[rr].y);
                u2.y = pack2(x[rr].z, x[rr].w);
                *(uint2*)&tile[(rql + rr) * HP + j * 8 + c * 2] = u2;
            }
        }
#pragma unroll
        for (int u = 0; u < 4; ++u) {
            const int dim = j * 16 + c * 4 + u;
            float4 s0 = *(const float4*)&sp[dim * 8];
            float4 s1 = *(const float4*)&sp[dim * 8 + 4];
#pragma unroll
            for (int rr = 0; rr < 4; ++rr) {
                const float xv = (u == 0) ? x[rr].x : (u == 1) ? x[rr].y
                               : (u == 2) ? x[rr].z : x[rr].w;
                d[rr][0] += xv * s0.x; d[rr][1] += xv * s0.y;
                d[rr][2] += xv * s0.z; d[rr][3] += xv * s0.w;
                d[rr][4] += xv * s1.x; d[rr][5] += xv * s1.y;
                d[rr][6] += xv * s1.z; d[rr][7] += xv * s1.w;
            }
        }
    }
#pragma unroll
    for (int rr = 0; rr < 4; ++rr)
#pragma unroll
        for (int p = 0; p < 8; ++p) {
            d[rr][p] += __shfl_xor(d[rr][p], 1);
            d[rr][p] += __shfl_xor(d[rr][p], 2);
        }
    int bits[4];
#pragma unroll
    for (int rr = 0; rr < 4; ++rr) {
        int bv = 0;
#pragma unroll
        for (int p = 0; p < 8; ++p) bv |= (d[rr][p] > 0.f) ? (1 << p) : 0;
        bits[rr] = bv;
    }
    const int myb = (c == 0) ? bits[0] : (c == 1) ? bits[1]
                  : (c == 2) ? bits[2] : bits[3];
    const int myrl = rql + c;                 // local row this lane emits
    ht[myrl & 15][myrl >> 4] = myb ^ (myb >> 1);
    __syncthreads();

    // ---- store phase ----
    if (isK) {
        uint4* dst = (uint4*)(kbf + blk * 256 * 64);   // block-contiguous 32KB
#pragma unroll
        for (int it = 0; it < 8; ++it) {
            const int g = it * 256 + t;                // 256 x 16B = 4KB / instr
            const unsigned int* sl = &tile[(g >> 3) * HP + (g & 7) * 4];
            uint4 val;
            val.x = sl[0]; val.y = sl[1]; val.z = sl[2]; val.w = sl[3];
            dst[g] = val;
        }
    }
    if (t < 64) {       // 16 h-planes x 4 int4 = 64 coalesced stores
        const int h2 = t >> 2, p2 = t & 3;
        int4 val = *(const int4*)&ht[h2][p2 * 4];
        const int gb = blk >> 9;                       // batch
        const int s0 = (blk * 16) & (S - 1);           // 16 s-values per block
        *(int4*)&hdst[(gb * H + h2) * S + s0 + p2 * 4] = val;
    }
}

// ---------------------------------------------------------------------------
// Kernel 2: stable counting sort.  (unchanged: pitch-257 hist, wave scan)
// ---------------------------------------------------------------------------
#define SORT_NT 64
#define SORT_CH (S / SORT_NT)   // 128
#define HPitch 257

__global__ __launch_bounds__(SORT_NT) void k_sort(const int* __restrict__ hq,
                                                  const int* __restrict__ hk,
                                                  int* __restrict__ qs,
                                                  int* __restrict__ ks) {
    __shared__ int hist[SORT_NT * HPitch];
    __shared__ int base[257];
    const int t  = threadIdx.x;
    const int bh = blockIdx.x & (BH - 1);
    const bool isQ = blockIdx.x < BH;
    const int* hp = (isQ ? hq : hk) + bh * S;
    int*       sp = (isQ ? qs : ks) + bh * S;

    for (int i = 0; i < HPitch; ++i) hist[t * HPitch + i] = 0;
    __syncthreads();
    for (int i = 0; i < SORT_CH; ++i) hist[t * HPitch + hp[t * SORT_CH + i]]++;
    __syncthreads();

    int v0 = 0, v1 = 0, v2 = 0, v3 = 0;
    for (int tt = 0; tt < SORT_NT; ++tt) {
        const int* hr = &hist[tt * HPitch + t * 4];
        v0 += hr[0]; v1 += hr[1]; v2 += hr[2]; v3 += hr[3];
    }
    {
        const int s1 = v0 + v1, s2 = s1 + v2, tot = s2 + v3;
        int inc = tot;
#pragma unroll
        for (int dlt = 1; dlt < 64; dlt <<= 1) {
            const int n = __shfl_up(inc, dlt);
            if (t >= dlt) inc += n;
        }
        const int ex = inc - tot;
        base[4 * t + 1] = ex + v0;
        base[4 * t + 2] = ex + s1;
        base[4 * t + 3] = ex + s2;
        base[4 * t + 4] = ex + tot;
        if (t == 0) base[0] = 0;
    }
    __syncthreads();

    for (int bi = 0; bi < 4; ++bi) {
        const int bin = t * 4 + bi;
        int run = base[bin];
        for (int tt = 0; tt < SORT_NT; ++tt) {
            int c = hist[tt * HPitch + bin];
            hist[tt * HPitch + bin] = run;
            run += c;
        }
    }
    __syncthreads();

    for (int i = 0; i < SORT_CH; ++i) {
        const int s0  = t * SORT_CH + i;
        const int bin = hp[s0];
        sp[hist[t * HPitch + bin]++] = s0;
    }
}

// ---------------------------------------------------------------------------
// Kernel 3: FUSED attention.  NEW vs R14: occupancy retest at 44 KB LDS.
//  (a) pL halved to 16 rows/wave: P write+read per-qg interleaved
//      (write qg0 -> read ap0 -> write qg1 -> read ap1; wave-ordered DS).
//  (b) __launch_bounds__(512,3): VGPR cap 85 (R15 proved this structure
//      fits 84 spill-free).  LDS 44.0 KB -> 3 blocks/CU even with 16 KB
//      allocation rounding (48*3=144 <= 160).
//  (c) pads VP 264 / PP 40 (16B-aligned; R16 showed 260/36 breaks b128).
//  (d) __expf restored (R17's exp2f = OCML accurate path, slower).
// Canaries: VGPR<=85, WRITE_SIZE 65536, Occupancy ~31% (else 2-block cap
// is structural -> revert to R14).
// ---------------------------------------------------------------------------
#define VP 264    // vT pitch (256 + 8 pad; 528 B rows, 16B-aligned)
#define PP 40     // per-wave P pitch (32 + 8 pad; 80 B rows, 16B-aligned)

__global__ __launch_bounds__(512, 3) void k_attn(const float* __restrict__ q,
                                                 const unsigned short* __restrict__ kbf,
                                                 const float* __restrict__ v,
                                                 const int* __restrict__ qs,
                                                 const int* __restrict__ ks,
                                                 const int* __restrict__ sidx,
                                                 float* __restrict__ out) {
    __shared__ __align__(16) unsigned short vT[64 * VP];       // 33792 B
    __shared__ __align__(16) unsigned short pL[8 * 16 * PP];   // 10240 B

    const int t    = threadIdx.x;
    const int w    = t >> 6;
    const int lane = t & 63;
    const int lg   = lane >> 4;      // 0..3
    const int lr   = lane & 15;      // 0..15
    // XCD swizzle: all 32 blocks of one (b,h) land on one XCD
    const int logical = (blockIdx.x & 7) * (BH * NB / 8) + (blockIdx.x >> 3);
    const int blk  = logical & (NB - 1);
    const int bh   = logical >> 5;
    const int h    = bh & (H - 1), b = bh >> 4;
    const int sbase = bh * S + blk * BS;
    unsigned short* pw = pL + w * 16 * PP;

    // ---- Q B-fragments from f32 (scale 1/8 folded into cvt) ----
    int qrow[2]; bf16x8 bq[2][2];
#pragma unroll
    for (int qg = 0; qg < 2; ++qg) {
        qrow[qg] = qs[sbase + w * 32 + qg * 16 + lr];
        const float* qp = q + (((b * S + qrow[qg]) * H + h) << 6);
#pragma unroll
        for (int kf = 0; kf < 2; ++kf) {
            float4 x0 = ((const float4*)(qp + kf * 32 + lg * 8))[0];
            float4 x1 = ((const float4*)(qp + kf * 32 + lg * 8))[1];
            union { bf16x8 v8; unsigned int u[4]; } fa;
            fa.u[0] = pack2(x0.x * 0.125f, x0.y * 0.125f);
            fa.u[1] = pack2(x0.z * 0.125f, x0.w * 0.125f);
            fa.u[2] = pack2(x1.x * 0.125f, x1.y * 0.125f);
            fa.u[3] = pack2(x1.z * 0.125f, x1.w * 0.125f);
            bq[qg][kf] = fa.v8;
        }
    }

    // ones-column B fragment: col 0 = 1.0 -> acc5 col0 accumulates sum(P)
    bf16x8 bv5;
    {
        union { bf16x8 v8; unsigned int u[4]; } fo;
        const unsigned int ov = (lr == 0) ? 0x3F803F80u : 0u;
        fo.u[0] = ov; fo.u[1] = ov; fo.u[2] = ov; fo.u[3] = ov;
        bv5 = fo.v8;
    }

    float m_run[2] = {-1e30f, -1e30f};
    f32x4 acc[2][4];
    f32x4 acc5[2];                     // l accumulator (col 0 = sum of P)
#pragma unroll
    for (int qg = 0; qg < 2; ++qg) {
        acc5[qg] = (f32x4){0.f, 0.f, 0.f, 0.f};
#pragma unroll
        for (int dg = 0; dg < 4; ++dg) acc[qg][dg] = (f32x4){0.f, 0.f, 0.f, 0.f};
    }

    for (int pass = 0; pass < 2; ++pass) {
        {   // ---- stage V^T from f32: load+convert EARLY, write after barrier
            const int key = t & 255, d0 = (t >> 8) * 32;
            const int krow = pass ? sidx[bh * SAMP + key] : ks[sbase + key];
            const float* vp = v + (((b * S + krow) * H + h) << 6) + d0;
            unsigned int uv[16];
#pragma unroll
            for (int i = 0; i < 8; ++i) {
                float4 y = ((const float4*)vp)[i];
                uv[2 * i]     = pack2(y.x, y.y);
                uv[2 * i + 1] = pack2(y.z, y.w);
            }
            if (pass) __syncthreads();          // all reads of old vT done
#pragma unroll
            for (int j = 0; j < 16; ++j) {
                const int d = d0 + 2 * j;
                vT[(d + 0) * VP + key] = (unsigned short)(uv[j]);
                vT[(d + 1) * VP + key] = (unsigned short)(uv[j] >> 16);
            }
        }
        __syncthreads();

        const float bias = pass ? LOG32 : 0.f;
#pragma unroll
        for (int kt4 = 0; kt4 < 4; ++kt4) {
            // ---- key rows + K-gathers for this tile ----
            int krw[4];
#pragma unroll
            for (int kg = 0; kg < 4; ++kg) {
                const int key = kt4 * 64 + kg * 16 + lr;
                krw[kg] = pass ? sidx[bh * SAMP + key] : ks[sbase + key];
            }
            // ---- S^T = K Q^T ----
            f32x4 c[2][4];
#pragma unroll
            for (int kf = 0; kf < 2; ++kf) {
                bf16x8 ak[4];
#pragma unroll
                for (int kg = 0; kg < 4; ++kg)
                    ak[kg] = *(const bf16x8*)(kbf + (((b * S + krw[kg]) * H + h) << 6)
                                              + kf * 32 + lg * 8);
                __builtin_amdgcn_s_setprio(1);
#pragma unroll
                for (int qg = 0; qg < 2; ++qg)
#pragma unroll
                    for (int kg = 0; kg < 4; ++kg) {
                        f32x4 cin = kf ? c[qg][kg] : (f32x4){0.f, 0.f, 0.f, 0.f};
                        c[qg][kg] = __builtin_amdgcn_mfma_f32_16x16x32_bf16(ak[kg], bq[qg][kf], cin, 0, 0, 0);
                    }
                __builtin_amdgcn_s_setprio(0);
            }

            // ---- online softmax: max + exp only (sum folded into PV) ----
#pragma unroll
            for (int qg = 0; qg < 2; ++qg) {
                float tm = -1e30f;
#pragma unroll
                for (int kg = 0; kg < 4; ++kg)
#pragma unroll
                    for (int r = 0; r < 4; ++r) tm = fmaxf(tm, c[qg][kg][r]);
                tm = fmaxf(tm, __shfl_xor(tm, 16));
                tm = fmaxf(tm, __shfl_xor(tm, 32));
                tm += bias;
                if (!__all(tm <= m_run[qg] + 8.f)) {
                    const float mn  = fmaxf(m_run[qg], tm);
                    const float es  = __expf(m_run[qg] - mn);
                    m_run[qg] = mn;
#pragma unroll
                    for (int r = 0; r < 4; ++r) {
                        const float er = __shfl(es, lg * 4 + r);
#pragma unroll
                        for (int dg = 0; dg < 4; ++dg) acc[qg][dg][r] *= er;
                        acc5[qg][r] *= er;
                    }
                }
                const float mnb = m_run[qg] - bias;
#pragma unroll
                for (int kg = 0; kg < 4; ++kg)
#pragma unroll
                    for (int r = 0; r < 4; ++r)
                        c[qg][kg][r] = __expf(c[qg][kg][r] - mnb);
            }
            // ---- PV in 32-key halves; P transpose via HALVED per-wave pL:
            //      write qg0 -> read ap0 -> write qg1 -> read ap1 (wave-ordered)
#pragma unroll
            for (int hh = 0; hh < 2; ++hh) {
                bf16x8 ap[2];
#pragma unroll
                for (int qg = 0; qg < 2; ++qg) {
#pragma unroll
                    for (int kg2 = 0; kg2 < 2; ++kg2) {
                        const int kg = hh * 2 + kg2;
                        uint2 u;
                        u.x = pack2(c[qg][kg][0], c[qg][kg][1]);
                        u.y = pack2(c[qg][kg][2], c[qg][kg][3]);
                        *(uint2*)&pw[lr * PP + kg2 * 16 + lg * 4] = u;
                    }
                    ap[qg] = *(const bf16x8*)&pw[lr * PP + lg * 8];
                }
                bf16x8 bv[4];
#pragma unroll
                for (int dg = 0; dg < 4; ++dg)
                    bv[dg] = *(const bf16x8*)&vT[(dg * 16 + lr) * VP + kt4 * 64 + hh * 32 + lg * 8];
                __builtin_amdgcn_s_setprio(1);
#pragma unroll
                for (int qg = 0; qg < 2; ++qg) {
#pragma unroll
                    for (int dg = 0; dg < 4; ++dg)
                        acc[qg][dg] = __builtin_amdgcn_mfma_f32_16x16x32_bf16(ap[qg], bv[dg], acc[qg][dg], 0, 0, 0);
                    acc5[qg] = __builtin_amdgcn_mfma_f32_16x16x32_bf16(ap[qg], bv5, acc5[qg], 0, 0, 0);
                }
                __builtin_amdgcn_s_setprio(0);
            }
        }
    }

    // ---- epilogue: out = acc / l; l = acc5 col 0 (lane lr==0 of lg group) ----
#pragma unroll
    for (int qg = 0; qg < 2; ++qg)
#pragma unroll
        for (int r = 0; r < 4; ++r) {
            const float lq = __shfl(acc5[qg][r], lg * 16);   // lane (lg, lr=0)
            const int   qr = __shfl(qrow[qg], lg * 4 + r);
            const float inv = 1.f / lq;
            const int obase = ((b * S + qr) * H + h) << 6;
#pragma unroll
            for (int dg = 0; dg < 4; ++dg)
                out[obase + dg * 16 + lr] = acc[qg][dg][r] * inv;
        }
}

// ---------------------------------------------------------------------------
extern "C" void kernel_launch(void* const* d_in, const int* in_sizes, int n_in,
                              void* d_out, int out_size, void* d_ws, size_t ws_size,
                              hipStream_t stream) {
    const float* q   = (const float*)d_in[0];
    const float* k   = (const float*)d_in[1];
    const float* v   = (const float*)d_in[2];
    const float* pd  = (const float*)d_in[3];
    const int*  sidx = (const int*)d_in[4];
    float* out = (float*)d_out;

    int* hq = (int*)d_ws;
    int* hk = hq + BHS;
    int* qs = hk + BHS;
    int* ks = qs + BHS;
    unsigned short* kbf = (unsigned short*)(ks + BHS);

    k_hash<<<2048, 256, 0, stream>>>(q, k, pd, hq, hk, kbf);
    k_sort<<<2 * BH, SORT_NT, 0, stream>>>(hq, hk, qs, ks);
    k_attn<<<BH * NB, 512, 0, stream>>>(q, kbf, v, qs, ks, sidx, out);
}

// Round 19
// 188.882 us; speedup vs baseline: 1.0733x; 1.0733x over previous
//
#include <hip/hip_runtime.h>
#include <hip/hip_bf16.h>

#define B 2
#define S 8192
#define H 16
#define D 64
#define NB 32          // S / BS
#define BS 256
#define SAMP 256
#define BH (B*H)
#define BHS (B*H*S)
#define BSHD (B*S*H*D)
#define LOG32 3.4657359027997265f   // log(8192/256)

typedef float f32x4 __attribute__((ext_vector_type(4)));
typedef short bf16x8 __attribute__((ext_vector_type(8)));

// Packed f32->bf16 (RNE), single HW instruction.
__device__ __forceinline__ unsigned int pack2(float a, float b) {
    unsigned int r;
    asm("v_cvt_pk_bf16_f32 %0, %1, %2" : "=v"(r) : "v"(a), "v"(b));
    return r;
}

// ---------------------------------------------------------------------------
// Kernel 1: LSH hash (Q and K) + bf16 pack of K.  Quad-cooperative compute
// (4 rows/quad, 16x64B fully-consumed read chunks; spd x4 at pitch 520).
// Stores via LDS tile -> 4KB-contiguous store instructions (R10 lesson:
// partial-sector stores amplify HBM writes 5.3x).  At cold-read floor.
// ---------------------------------------------------------------------------
#define HP 34   // tile pitch in dwords (136 B / row)

__global__ __launch_bounds__(256, 3) void k_hash(const float* __restrict__ q,
                                                 const float* __restrict__ k,
                                                 const float* __restrict__ pd,
                                                 int* __restrict__ hq,
                                                 int* __restrict__ hk,
                                                 unsigned short* __restrict__ kbf) {
    __shared__ float spd4[4 * 520];          // 8320 B
    __shared__ unsigned int tile[256 * HP];  // 34816 B
    __shared__ int ht[16][16];               // 1024 B
    const int t = threadIdx.x;
    for (int i = t; i < 512; i += 256) {
        const float val = pd[i];
        spd4[i] = val; spd4[520 + i] = val;
        spd4[1040 + i] = val; spd4[1560 + i] = val;
    }
    __syncthreads();

    const bool isK = blockIdx.x >= 1024;
    const int  blk = blockIdx.x & 1023;
    const float* src = isK ? k : q;
    int* hdst = isK ? hk : hq;

    const int lane = t & 63;
    const int c    = lane & 3;                          // dim-quarter owner
    const int rql  = (t >> 6) * 64 + (lane >> 2) * 4;   // local row base of quad
    const int rowq = blk * 256 + rql;
    const float* sp = spd4 + c * 520;

    float d[4][8];
#pragma unroll
    for (int rr = 0; rr < 4; ++rr)
#pragma unroll
        for (int p = 0; p < 8; ++p) d[rr][p] = 0.f;

#pragma unroll
    for (int j = 0; j < 4; ++j) {
        float4 x[4];
#pragma unroll
        for (int rr = 0; rr < 4; ++rr)
            x[rr] = *(const float4*)(src + ((rowq + rr) << 6) + j * 16 + c * 4);

        if (isK) {
#pragma unroll
            for (int rr = 0; rr < 4; ++rr) {
                uint2 u2;
                u2.x = pack2(x[rr].x, x[rr].y);
                u2.y = pack2(x[rr].z, x[rr].w);
                *(uint2*)&tile[(rql + rr) * HP + j * 8 + c * 2] = u2;
            }
        }
#pragma unroll
        for (int u = 0; u < 4; ++u) {
            const int dim = j * 16 + c * 4 + u;
            float4 s0 = *(const float4*)&sp[dim * 8];
            float4 s1 = *(const float4*)&sp[dim * 8 + 4];
#pragma unroll
            for (int rr = 0; rr < 4; ++rr) {
                const float xv = (u == 0) ? x[rr].x : (u == 1) ? x[rr].y
                               : (u == 2) ? x[rr].z : x[rr].w;
                d[rr][0] += xv * s0.x; d[rr][1] += xv * s0.y;
                d[rr][2] += xv * s0.z; d[rr][3] += xv * s0.w;
                d[rr][4] += xv * s1.x; d[rr][5] += xv * s1.y;
                d[rr][6] += xv * s1.z; d[rr][7] += xv * s1.w;
            }
        }
    }
#pragma unroll
    for (int rr = 0; rr < 4; ++rr)
#pragma unroll
        for (int p = 0; p < 8; ++p) {
            d[rr][p] += __shfl_xor(d[rr][p], 1);
            d[rr][p] += __shfl_xor(d[rr][p], 2);
        }
    int bits[4];
#pragma unroll
    for (int rr = 0; rr < 4; ++rr) {
        int bv = 0;
#pragma unroll
        for (int p = 0; p < 8; ++p) bv |= (d[rr][p] > 0.f) ? (1 << p) : 0;
        bits[rr] = bv;
    }
    const int myb = (c == 0) ? bits[0] : (c == 1) ? bits[1]
                  : (c == 2) ? bits[2] : bits[3];
    const int myrl = rql + c;                 // local row this lane emits
    ht[myrl & 15][myrl >> 4] = myb ^ (myb >> 1);
    __syncthreads();

    // ---- store phase ----
    if (isK) {
        uint4* dst = (uint4*)(kbf + blk * 256 * 64);   // block-contiguous 32KB
#pragma unroll
        for (int it = 0; it < 8; ++it) {
            const int g = it * 256 + t;                // 256 x 16B = 4KB / instr
            const unsigned int* sl = &tile[(g >> 3) * HP + (g & 7) * 4];
            uint4 val;
            val.x = sl[0]; val.y = sl[1]; val.z = sl[2]; val.w = sl[3];
            dst[g] = val;
        }
    }
    if (t < 64) {       // 16 h-planes x 4 int4 = 64 coalesced stores
        const int h2 = t >> 2, p2 = t & 3;
        int4 val = *(const int4*)&ht[h2][p2 * 4];
        const int gb = blk >> 9;                       // batch
        const int s0 = (blk * 16) & (S - 1);           // 16 s-values per block
        *(int4*)&hdst[(gb * H + h2) * S + s0 + p2 * 4] = val;
    }
}

// ---------------------------------------------------------------------------
// Kernel 2: stable counting sort (pitch-257 hist, wave-parallel prefix scan)
// ---------------------------------------------------------------------------
#define SORT_NT 64
#define SORT_CH (S / SORT_NT)   // 128
#define HPitch 257

__global__ __launch_bounds__(SORT_NT) void k_sort(const int* __restrict__ hq,
                                                  const int* __restrict__ hk,
                                                  int* __restrict__ qs,
                                                  int* __restrict__ ks) {
    __shared__ int hist[SORT_NT * HPitch];
    __shared__ int base[257];
    const int t  = threadIdx.x;
    const int bh = blockIdx.x & (BH - 1);
    const bool isQ = blockIdx.x < BH;
    const int* hp = (isQ ? hq : hk) + bh * S;
    int*       sp = (isQ ? qs : ks) + bh * S;

    for (int i = 0; i < HPitch; ++i) hist[t * HPitch + i] = 0;
    __syncthreads();
    for (int i = 0; i < SORT_CH; ++i) hist[t * HPitch + hp[t * SORT_CH + i]]++;
    __syncthreads();

    int v0 = 0, v1 = 0, v2 = 0, v3 = 0;
    for (int tt = 0; tt < SORT_NT; ++tt) {
        const int* hr = &hist[tt * HPitch + t * 4];
        v0 += hr[0]; v1 += hr[1]; v2 += hr[2]; v3 += hr[3];
    }
    {
        const int s1 = v0 + v1, s2 = s1 + v2, tot = s2 + v3;
        int inc = tot;
#pragma unroll
        for (int dlt = 1; dlt < 64; dlt <<= 1) {
            const int n = __shfl_up(inc, dlt);
            if (t >= dlt) inc += n;
        }
        const int ex = inc - tot;
        base[4 * t + 1] = ex + v0;
        base[4 * t + 2] = ex + s1;
        base[4 * t + 3] = ex + s2;
        base[4 * t + 4] = ex + tot;
        if (t == 0) base[0] = 0;
    }
    __syncthreads();

    for (int bi = 0; bi < 4; ++bi) {
        const int bin = t * 4 + bi;
        int run = base[bin];
        for (int tt = 0; tt < SORT_NT; ++tt) {
            int c = hist[tt * HPitch + bin];
            hist[tt * HPitch + bin] = run;
            run += c;
        }
    }
    __syncthreads();

    for (int i = 0; i < SORT_CH; ++i) {
        const int s0  = t * SORT_CH + i;
        const int bin = hp[s0];
        sp[hist[t * HPitch + bin]++] = s0;
    }
}

// ---------------------------------------------------------------------------
// Kernel 3: FUSED attention — R14 configuration (measured optimum).
// (512,2): VGPR budget 128, 2 blocks/CU (structural cap, R15/R18).
// VP 264 / PP 40: 16B-aligned LDS pitches (R16: smaller pads break b128).
// l folded into PV via ones-column (acc5); defer-max; __expf; K-prefetch
// rotation; V staged from f32 issue-early with pre-barrier cvt_pk pack.
// ---------------------------------------------------------------------------
#define VP 264    // vT pitch (256 + 8 pad; 528 B rows, 16B-aligned)
#define PP 40     // per-wave P pitch (32 + 8 pad; 80 B rows, 16B-aligned)

__global__ __launch_bounds__(512, 2) void k_attn(const float* __restrict__ q,
                                                 const unsigned short* __restrict__ kbf,
                                                 const float* __restrict__ v,
                                                 const int* __restrict__ qs,
                                                 const int* __restrict__ ks,
                                                 const int* __restrict__ sidx,
                                                 float* __restrict__ out) {
    __shared__ __align__(16) unsigned short vT[64 * VP];
    __shared__ __align__(16) unsigned short pL[8 * 32 * PP];

    const int t    = threadIdx.x;
    const int w    = t >> 6;
    const int lane = t & 63;
    const int lg   = lane >> 4;      // 0..3
    const int lr   = lane & 15;      // 0..15
    // XCD swizzle: all 32 blocks of one (b,h) land on one XCD
    const int logical = (blockIdx.x & 7) * (BH * NB / 8) + (blockIdx.x >> 3);
    const int blk  = logical & (NB - 1);
    const int bh   = logical >> 5;
    const int h    = bh & (H - 1), b = bh >> 4;
    const int sbase = bh * S + blk * BS;
    unsigned short* pw = pL + w * 32 * PP;

    // ---- Q B-fragments from f32 (scale 1/8 folded into cvt) ----
    int qrow[2]; bf16x8 bq[2][2];
#pragma unroll
    for (int qg = 0; qg < 2; ++qg) {
        qrow[qg] = qs[sbase + w * 32 + qg * 16 + lr];
        const float* qp = q + (((b * S + qrow[qg]) * H + h) << 6);
#pragma unroll
        for (int kf = 0; kf < 2; ++kf) {
            float4 x0 = ((const float4*)(qp + kf * 32 + lg * 8))[0];
            float4 x1 = ((const float4*)(qp + kf * 32 + lg * 8))[1];
            union { bf16x8 v8; unsigned int u[4]; } fa;
            fa.u[0] = pack2(x0.x * 0.125f, x0.y * 0.125f);
            fa.u[1] = pack2(x0.z * 0.125f, x0.w * 0.125f);
            fa.u[2] = pack2(x1.x * 0.125f, x1.y * 0.125f);
            fa.u[3] = pack2(x1.z * 0.125f, x1.w * 0.125f);
            bq[qg][kf] = fa.v8;
        }
    }

    // ones-column B fragment: col 0 = 1.0 -> acc5 col0 accumulates sum(P)
    bf16x8 bv5;
    {
        union { bf16x8 v8; unsigned int u[4]; } fo;
        const unsigned int ov = (lr == 0) ? 0x3F803F80u : 0u;
        fo.u[0] = ov; fo.u[1] = ov; fo.u[2] = ov; fo.u[3] = ov;
        bv5 = fo.v8;
    }

    float m_run[2] = {-1e30f, -1e30f};
    f32x4 acc[2][4];
    f32x4 acc5[2];                     // l accumulator (col 0 = sum of P)
#pragma unroll
    for (int qg = 0; qg < 2; ++qg) {
        acc5[qg] = (f32x4){0.f, 0.f, 0.f, 0.f};
#pragma unroll
        for (int dg = 0; dg < 4; ++dg) acc[qg][dg] = (f32x4){0.f, 0.f, 0.f, 0.f};
    }

    for (int pass = 0; pass < 2; ++pass) {
        {   // ---- stage V^T from f32: load+convert EARLY, write after barrier
            const int key = t & 255, d0 = (t >> 8) * 32;
            const int krow = pass ? sidx[bh * SAMP + key] : ks[sbase + key];
            const float* vp = v + (((b * S + krow) * H + h) << 6) + d0;
            unsigned int uv[16];
#pragma unroll
            for (int i = 0; i < 8; ++i) {
                float4 y = ((const float4*)vp)[i];
                uv[2 * i]     = pack2(y.x, y.y);
                uv[2 * i + 1] = pack2(y.z, y.w);
            }
            if (pass) __syncthreads();          // all reads of old vT done
#pragma unroll
            for (int j = 0; j < 16; ++j) {
                const int d = d0 + 2 * j;
                vT[(d + 0) * VP + key] = (unsigned short)(uv[j]);
                vT[(d + 1) * VP + key] = (unsigned short)(uv[j] >> 16);
            }
        }
        __syncthreads();

        const float bias = pass ? LOG32 : 0.f;

        // ---- prefetch tile 0: key indices + kf0 K-fragments ----
        int krw[4]; bf16x8 akp[4];
#pragma unroll
        for (int kg = 0; kg < 4; ++kg) {
            const int key = kg * 16 + lr;
            krw[kg] = pass ? sidx[bh * SAMP + key] : ks[sbase + key];
        }
#pragma unroll
        for (int kg = 0; kg < 4; ++kg)
            akp[kg] = *(const bf16x8*)(kbf + (((b * S + krw[kg]) * H + h) << 6) + lg * 8);

#pragma unroll
        for (int kt4 = 0; kt4 < 4; ++kt4) {
            // kf=1 fragments for the current tile
            bf16x8 ak1[4];
#pragma unroll
            for (int kg = 0; kg < 4; ++kg)
                ak1[kg] = *(const bf16x8*)(kbf + (((b * S + krw[kg]) * H + h) << 6)
                                           + 32 + lg * 8);
            // ---- S^T = K Q^T ----
            f32x4 c[2][4];
            __builtin_amdgcn_s_setprio(1);
#pragma unroll
            for (int qg = 0; qg < 2; ++qg)
#pragma unroll
                for (int kg = 0; kg < 4; ++kg) {
                    f32x4 z = (f32x4){0.f, 0.f, 0.f, 0.f};
                    z = __builtin_amdgcn_mfma_f32_16x16x32_bf16(akp[kg], bq[qg][0], z, 0, 0, 0);
                    c[qg][kg] = __builtin_amdgcn_mfma_f32_16x16x32_bf16(ak1[kg], bq[qg][1], z, 0, 0, 0);
                }
            __builtin_amdgcn_s_setprio(0);

            // ---- prefetch NEXT tile (latency hides under softmax + PV) ----
            int krwn[4]; bf16x8 akn[4];
            if (kt4 < 3) {
#pragma unroll
                for (int kg = 0; kg < 4; ++kg) {
                    const int key = (kt4 + 1) * 64 + kg * 16 + lr;
                    krwn[kg] = pass ? sidx[bh * SAMP + key] : ks[sbase + key];
                }
#pragma unroll
                for (int kg = 0; kg < 4; ++kg)
                    akn[kg] = *(const bf16x8*)(kbf + (((b * S + krwn[kg]) * H + h) << 6)
                                               + lg * 8);
            }

            // ---- online softmax: max + exp only (sum folded into PV) ----
#pragma unroll
            for (int qg = 0; qg < 2; ++qg) {
                float tm = -1e30f;
#pragma unroll
                for (int kg = 0; kg < 4; ++kg)
#pragma unroll
                    for (int r = 0; r < 4; ++r) tm = fmaxf(tm, c[qg][kg][r]);
                tm = fmaxf(tm, __shfl_xor(tm, 16));
                tm = fmaxf(tm, __shfl_xor(tm, 32));
                tm += bias;
                if (!__all(tm <= m_run[qg] + 8.f)) {
                    const float mn  = fmaxf(m_run[qg], tm);
                    const float es  = __expf(m_run[qg] - mn);
                    m_run[qg] = mn;
#pragma unroll
                    for (int r = 0; r < 4; ++r) {
                        const float er = __shfl(es, lg * 4 + r);
#pragma unroll
                        for (int dg = 0; dg < 4; ++dg) acc[qg][dg][r] *= er;
                        acc5[qg][r] *= er;
                    }
                }
                const float mnb = m_run[qg] - bias;
#pragma unroll
                for (int kg = 0; kg < 4; ++kg)
#pragma unroll
                    for (int r = 0; r < 4; ++r)
                        c[qg][kg][r] = __expf(c[qg][kg][r] - mnb);
            }
            // ---- PV in 32-key halves: packed P write (cvt_pk), b128 reads ----
#pragma unroll
            for (int hh = 0; hh < 2; ++hh) {
#pragma unroll
                for (int qg = 0; qg < 2; ++qg)
#pragma unroll
                    for (int kg2 = 0; kg2 < 2; ++kg2) {
                        const int kg = hh * 2 + kg2;
                        uint2 u;
                        u.x = pack2(c[qg][kg][0], c[qg][kg][1]);
                        u.y = pack2(c[qg][kg][2], c[qg][kg][3]);
                        *(uint2*)&pw[(qg * 16 + lr) * PP + kg2 * 16 + lg * 4] = u;
                    }
                bf16x8 bv[4];
#pragma unroll
                for (int dg = 0; dg < 4; ++dg)
                    bv[dg] = *(const bf16x8*)&vT[(dg * 16 + lr) * VP + kt4 * 64 + hh * 32 + lg * 8];
                bf16x8 ap[2];
#pragma unroll
                for (int qg = 0; qg < 2; ++qg)
                    ap[qg] = *(const bf16x8*)&pw[(qg * 16 + lr) * PP + lg * 8];
                __builtin_amdgcn_s_setprio(1);
#pragma unroll
                for (int qg = 0; qg < 2; ++qg) {
#pragma unroll
                    for (int dg = 0; dg < 4; ++dg)
                        acc[qg][dg] = __builtin_amdgcn_mfma_f32_16x16x32_bf16(ap[qg], bv[dg], acc[qg][dg], 0, 0, 0);
                    acc5[qg] = __builtin_amdgcn_mfma_f32_16x16x32_bf16(ap[qg], bv5, acc5[qg], 0, 0, 0);
                }
                __builtin_amdgcn_s_setprio(0);
            }

            // rotate prefetched tile into place
            if (kt4 < 3) {
#pragma unroll
                for (int kg = 0; kg < 4; ++kg) { krw[kg] = krwn[kg]; akp[kg] = akn[kg]; }
            }
        }
    }

    // ---- epilogue: out = acc / l; l = acc5 col 0 (lane lr==0 of lg group) ----
#pragma unroll
    for (int qg = 0; qg < 2; ++qg)
#pragma unroll
        for (int r = 0; r < 4; ++r) {
            const float lq = __shfl(acc5[qg][r], lg * 16);   // lane (lg, lr=0)
            const int   qr = __shfl(qrow[qg], lg * 4 + r);
            const float inv = 1.f / lq;
            const int obase = ((b * S + qr) * H + h) << 6;
#pragma unroll
            for (int dg = 0; dg < 4; ++dg)
                out[obase + dg * 16 + lr] = acc[qg][dg][r] * inv;
        }
}

// ---------------------------------------------------------------------------
extern "C" void kernel_launch(void* const* d_in, const int* in_sizes, int n_in,
                              void* d_out, int out_size, void* d_ws, size_t ws_size,
                              hipStream_t stream) {
    const float* q   = (const float*)d_in[0];
    const float* k   = (const float*)d_in[1];
    const float* v   = (const float*)d_in[2];
    const float* pd  = (const float*)d_in[3];
    const int*  sidx = (const int*)d_in[4];
    float* out = (float*)d_out;

    int* hq = (int*)d_ws;
    int* hk = hq + BHS;
    int* qs = hk + BHS;
    int* ks = qs + BHS;
    unsigned short* kbf = (unsigned short*)(ks + BHS);

    k_hash<<<2048, 256, 0, stream>>>(q, k, pd, hq, hk, kbf);
    k_sort<<<2 * BH, SORT_NT, 0, stream>>>(hq, hk, qs, ks);
    k_attn<<<BH * NB, 512, 0, stream>>>(q, kbf, v, qs, ks, sidx, out);
}